// Round 3
// baseline (1571.050 us; speedup 1.0000x reference)
//
#include <hip/hip_runtime.h>
#include <cstdint>
#include <cstddef>

// Problem constants
#define B_  512
#define T_  256
#define D_  256
#define H_  1024
#define K2  512      // effective K = 2*D: [ m*x | m ]; mu-path folded into cvec/Wb
#define N2  2048     // interleaved outputs: col 2m = z preact, col 2m+1 = h_til preact
#define TC  32       // timesteps per chunk
#define NCHUNK 8     // TC*NCHUNK == T_

// Workspace layout (bytes). Total ~36 MB.
#define OFF_WB    ((size_t)0)                      // bf16 [2048][512]            2 MB
#define OFF_CVEC  ((size_t)2097152)                // f32  [2048]                 8 KB
#define OFF_H     ((size_t)2105344)                // f32  [B][H]                 2 MB
#define OFF_PQ    ((size_t)4202496)                // f32x2 [NCHUNK][B][H]       32 MB

typedef short   bf16x8 __attribute__((ext_vector_type(8)));   // 8 bf16 (4 VGPRs)
typedef float   f32x4  __attribute__((ext_vector_type(4)));

__device__ __forceinline__ unsigned short f2bf(float f) {
    unsigned int u = __float_as_uint(f);
    u += 0x7fffu + ((u >> 16) & 1u);   // round-to-nearest-even
    return (unsigned short)(u >> 16);
}

// ---- Prep: effective weights, bf16 [2048][512], z/h rows interleaved.
// cols [0:D) = W1; cols [D:2D) = W3 - W1*mu.  (M binary => x_tilde = m*x+(1-m)*mu:
// preact = W1.(m*x) + (W3 - W1*mu).m + [(W1+W2).mu + bias]) ----
__global__ void build_wb(const float* __restrict__ Wz, const float* __restrict__ Wh,
                         const float* __restrict__ xm, unsigned short* __restrict__ Wb) {
    int e = blockIdx.x * 256 + threadIdx.x;        // 2048*512 elems
    int r = e >> 9;
    int k = e & 511;
    int m = r >> 1;
    const float* W = (r & 1) ? (Wh + (size_t)m * 768) : (Wz + (size_t)m * 768);
    float v = (k < D_) ? W[k]
                       : (W[2 * D_ + (k - D_)] - W[k - D_] * xm[k - D_]);
    Wb[e] = f2bf(v);
}

// ---- Prep: cvec[r] = bias[r] + (W1[r,:] + W2[r,:]) . mu  (interleaved rows) ----
__global__ void build_cvec(const float* __restrict__ Wz, const float* __restrict__ bz,
                           const float* __restrict__ Wh, const float* __restrict__ bh,
                           const float* __restrict__ xm, float* __restrict__ cvec) {
    int r = blockIdx.x;           // 0..2047
    int m = r >> 1;
    int d = threadIdx.x;          // 0..255
    const float* W = (r & 1) ? (Wh + (size_t)m * 768) : (Wz + (size_t)m * 768);
    float v = (W[d] + W[D_ + d]) * xm[d];
    for (int off = 32; off; off >>= 1) v += __shfl_down(v, off);
    __shared__ float red[4];
    if ((d & 63) == 0) red[d >> 6] = v;
    __syncthreads();
    if (d == 0) {
        float bias = (r & 1) ? bh[m] : bz[m];
        cvec[r] = bias + red[0] + red[1] + red[2] + red[3];
    }
}

// ---- Fused build + GEMM + activation + chunk-local scan.
// One block per 128-row panel (4 batches x 32 timesteps).  8 waves.
// Phase 1: build A-tile (bf16 [128][K2], padded stride 520) in LDS from X,M.
// Phase 2 (NO barriers): each wave owns 256 output cols; per 64-col group,
//   K-loop reads A-frags from LDS (2-way banks, free) and W-frags DIRECTLY
//   from global (L2-resident, 2 MB); 32 MFMA per K-step; acc[8][4].
// Epilogue: activation in regs -> pair exchange (shfl_xor 1) -> in-lane 4-step
//   affine compose -> ordered q-butterfly (shfl_xor 16/32) -> store (P,Q).
#define ASTRIDE 520   // ushorts/row = 65 quads (odd) -> conflict-free b128 frag reads
__global__ __launch_bounds__(512, 2) void gemm_scan(
    const float* __restrict__ X,               // [B][T][D] f32
    const float* __restrict__ Mm,              // [B][T][D] f32 (binary)
    const unsigned short* __restrict__ W,      // [2048][512] bf16, z/h interleaved
    const float* __restrict__ cvec,            // [2048]
    float2* __restrict__ PQ)                   // [NCHUNK][B][1024]
{
    __shared__ __align__(16) unsigned short As[128 * ASTRIDE];   // 133,120 B
    const int tid  = threadIdx.x;
    const int lane = tid & 63;
    const int w    = tid >> 6;
    const int p    = blockIdx.x;          // panel 0..1023
    const int c    = p >> 7;              // chunk
    const int bg0  = (p & 127) * 4;       // first global batch of panel

    // ---- Phase 1: build A rows. row = bl*32 + tc; lanes 0-31: m*x, 32-63: m ----
    {
        const int half = lane >> 5;
        const int d    = (lane & 31) * 8;
        #pragma unroll
        for (int j = 0; j < 16; ++j) {
            const int row = w + 8 * j;                       // each row once
            const int b   = bg0 + (row >> 5);
            const int t   = c * TC + (row & 31);
            const size_t base = ((size_t)b * T_ + t) * D_ + d;
            const float4* mp = (const float4*)(Mm + base);
            float4 m0 = mp[0], m1 = mp[1];
            float v[8];
            if (half == 0) {
                const float4* xp = (const float4*)(X + base);
                float4 x0 = xp[0], x1 = xp[1];
                v[0]=m0.x*x0.x; v[1]=m0.y*x0.y; v[2]=m0.z*x0.z; v[3]=m0.w*x0.w;
                v[4]=m1.x*x1.x; v[5]=m1.y*x1.y; v[6]=m1.z*x1.z; v[7]=m1.w*x1.w;
            } else {
                v[0]=m0.x; v[1]=m0.y; v[2]=m0.z; v[3]=m0.w;
                v[4]=m1.x; v[5]=m1.y; v[6]=m1.z; v[7]=m1.w;
            }
            uint4 pk;
            pk.x = (unsigned)f2bf(v[0]) | ((unsigned)f2bf(v[1]) << 16);
            pk.y = (unsigned)f2bf(v[2]) | ((unsigned)f2bf(v[3]) << 16);
            pk.z = (unsigned)f2bf(v[4]) | ((unsigned)f2bf(v[5]) << 16);
            pk.w = (unsigned)f2bf(v[6]) | ((unsigned)f2bf(v[7]) << 16);
            *(uint4*)&As[row * ASTRIDE + lane * 8] = pk;     // lane*16B, linear
        }
    }
    __syncthreads();   // the ONLY block-wide barrier

    const int l15 = lane & 15;
    const int q8  = (lane >> 4) * 8;       // k sub-offset (ushorts) within 32-K chunk
    const float par = (float)(lane & 1);   // col parity: 0 => z (sigmoid), 1 => h~ (tanh)
    const float sg  = 1.f + par;

    for (int ci = 0; ci < 4; ++ci) {
        const int nbase = w * 256 + ci * 64;
        // 4 global W base pointers (16 imm-offset b128 loads each)
        const unsigned short* wp0 = W + (size_t)(nbase +  0 + l15) * K2 + q8;
        const unsigned short* wp1 = wp0 + 16 * K2;
        const unsigned short* wp2 = wp0 + 32 * K2;
        const unsigned short* wp3 = wp0 + 48 * K2;

        f32x4 acc[8][4] = {};
        #pragma unroll
        for (int kk = 0; kk < 16; ++kk) {
            bf16x8 af[8], bv[4];
            #pragma unroll
            for (int i = 0; i < 8; ++i)
                af[i] = *(const bf16x8*)&As[(i * 16 + l15) * ASTRIDE + q8 + kk * 32];
            bv[0] = *(const bf16x8*)(wp0 + kk * 32);
            bv[1] = *(const bf16x8*)(wp1 + kk * 32);
            bv[2] = *(const bf16x8*)(wp2 + kk * 32);
            bv[3] = *(const bf16x8*)(wp3 + kk * 32);
            #pragma unroll
            for (int i = 0; i < 8; ++i)
                #pragma unroll
                for (int j = 0; j < 4; ++j)
                    acc[i][j] = __builtin_amdgcn_mfma_f32_16x16x32_bf16(af[i], bv[j], acc[i][j], 0, 0, 0);
        }

        // ---- epilogue: per col-group j, per batch bl: activation + affine scan ----
        #pragma unroll
        for (int j = 0; j < 4; ++j) {
            const float cadd = cvec[nbase + j * 16 + l15];
            #pragma unroll
            for (int bl = 0; bl < 4; ++bl) {
                // lane holds rows {16*i2 + 4q + r} of batch bl (q = lane>>4), i = 2bl+i2
                float PA = 1.f, QA = 0.f, PB = 1.f, QB = 0.f;
                #pragma unroll
                for (int r = 0; r < 4; ++r) {
                    {   // i2 = 0: t = 4q + r
                        float v  = acc[2 * bl][j][r] + cadd;
                        float a  = sg / (1.f + __expf(-sg * v)) - par;  // sig or tanh
                        float ap = __shfl_xor(a, 1);
                        float z  = (lane & 1) ? ap : a;
                        float ht = (lane & 1) ? a : ap;
                        float om = 1.f - z;
                        QA = om * QA + z * ht;
                        PA = om * PA;
                    }
                    {   // i2 = 1: t = 16 + 4q + r
                        float v  = acc[2 * bl + 1][j][r] + cadd;
                        float a  = sg / (1.f + __expf(-sg * v)) - par;
                        float ap = __shfl_xor(a, 1);
                        float z  = (lane & 1) ? ap : a;
                        float ht = (lane & 1) ? a : ap;
                        float om = 1.f - z;
                        QB = om * QB + z * ht;
                        PB = om * PB;
                    }
                }
                // ordered butterfly over q (lane bits 4,5): lower q = earlier time
                #pragma unroll
                for (int s = 16; s <= 32; s <<= 1) {
                    float PAp = __shfl_xor(PA, s), QAp = __shfl_xor(QA, s);
                    float PBp = __shfl_xor(PB, s), QBp = __shfl_xor(QB, s);
                    const bool late = (lane & s) != 0;
                    float Pe = late ? PAp : PA,  Qe = late ? QAp : QA;
                    float Pl = late ? PA  : PAp, Ql = late ? QA  : QAp;
                    PA = Pl * Pe;  QA = Pl * Qe + Ql;
                    Pe = late ? PBp : PB;  Qe = late ? QBp : QB;
                    Pl = late ? PB  : PBp; Ql = late ? QB  : QBp;
                    PB = Pl * Pe;  QB = Pl * Qe + Ql;
                }
                // total over 32 steps: apply A (t=0..15) then B (t=16..31)
                const float Ptot = PB * PA;
                const float Qtot = PB * QA + QB;
                if (((lane >> 4) == bl) && ((lane & 1) == 0)) {
                    const int npg = (nbase + j * 16 + l15) >> 1;   // original hidden idx
                    PQ[((size_t)c * B_ + bg0 + bl) * H_ + npg] = make_float2(Ptot, Qtot);
                }
            }
        }
    }
}

// ---- Combine the 8 chunk-affine maps: h = P_c*h + Q_c, c = 0..7 ----
__global__ void combine(const float2* __restrict__ PQ, float* __restrict__ hbuf) {
    int v = blockIdx.x * 256 + threadIdx.x;   // B*H threads
    int b = v >> 10;
    int n = v & 1023;
    float h = 0.f;
    #pragma unroll
    for (int c = 0; c < NCHUNK; c++) {
        float2 pq = PQ[((size_t)c * B_ + b) * H_ + n];
        h = pq.x * h + pq.y;
    }
    hbuf[(size_t)b * H_ + n] = h;
}

// ---- Output head: out[b] = sigmoid(h[b,:] . Wout + bout) ----
__global__ void head(const float* __restrict__ hbuf, const float* __restrict__ Wout,
                     const float* __restrict__ bout, float* __restrict__ out) {
    int b = blockIdx.x;
    float s = 0.f;
    for (int n = threadIdx.x; n < H_; n += 256)
        s += hbuf[(size_t)b * H_ + n] * Wout[n];
    for (int off = 32; off; off >>= 1) s += __shfl_down(s, off);
    __shared__ float red[4];
    if ((threadIdx.x & 63) == 0) red[threadIdx.x >> 6] = s;
    __syncthreads();
    if (threadIdx.x == 0) {
        float t = red[0] + red[1] + red[2] + red[3] + bout[0];
        out[b] = 1.f / (1.f + expf(-t));
    }
}

extern "C" void kernel_launch(void* const* d_in, const int* in_sizes, int n_in,
                              void* d_out, int out_size, void* d_ws, size_t ws_size,
                              hipStream_t stream) {
    const float* X    = (const float*)d_in[0];
    const float* Mm   = (const float*)d_in[1];
    const float* xm   = (const float*)d_in[2];
    // d_in[3]=gamma_x: algebraically irrelevant for binary masks (x_tilde == m*x+(1-m)*mu)
    const float* Wz   = (const float*)d_in[4];
    const float* bz   = (const float*)d_in[5];
    // d_in[6]=Wr, d_in[7]=br: dead code in reference (r_t unused) — skipped
    const float* Wh   = (const float*)d_in[8];
    const float* bh   = (const float*)d_in[9];
    const float* Wout = (const float*)d_in[10];
    const float* bout = (const float*)d_in[11];
    float* out = (float*)d_out;

    char* ws = (char*)d_ws;
    unsigned short* Wb    = (unsigned short*)(ws + OFF_WB);
    float*          cvec  = (float*)(ws + OFF_CVEC);
    float*          hbuf  = (float*)(ws + OFF_H);
    float2*         PQ    = (float2*)(ws + OFF_PQ);

    build_wb  <<<dim3(N2 * K2 / 256), dim3(256), 0, stream>>>(Wz, Wh, xm, Wb);
    build_cvec<<<dim3(N2),            dim3(256), 0, stream>>>(Wz, bz, Wh, bh, xm, cvec);

    // one block per 128-row panel; A built in-kernel (no inp2 pass, no gates pass)
    gemm_scan<<<dim3(NCHUNK * TC * B_ / 128), dim3(512), 0, stream>>>(X, Mm, Wb, cvec, PQ);

    combine<<<dim3(B_ * H_ / 256), dim3(256), 0, stream>>>(PQ, hbuf);
    head   <<<dim3(B_),            dim3(256), 0, stream>>>(hbuf, Wout, bout, out);
}

// Round 4
// 721.977 us; speedup vs baseline: 2.1760x; 2.1760x over previous
//
#include <hip/hip_runtime.h>
#include <cstdint>
#include <cstddef>

// Problem constants
#define B_  512
#define T_  256
#define D_  256
#define H_  1024
#define K2  512      // effective K = 2*D: [ m*x | m ]; mu-path folded into cvec/Wb
#define N2  2048     // interleaved outputs: col 2m = z preact, col 2m+1 = h_til preact
#define TC  32       // timesteps per chunk
#define NCHUNK 8     // TC*NCHUNK == T_

// Workspace layout (bytes). Needs ~172 MB (proven available in round 2).
#define OFF_WB    ((size_t)0)                      // bf16 [8][16][256][32]       2 MB
#define OFF_CVEC  ((size_t)2097152)                // f32  [2048]                 8 KB
#define OFF_H     ((size_t)2105344)                // f32  [B][H]                 2 MB
#define OFF_PQ    ((size_t)4202496)                // f32x2 [NCHUNK][B][H]       32 MB
#define OFF_INP2  ((size_t)37756928)               // bf16 [1024][16][128][32]  128 MB

typedef short   bf16x8 __attribute__((ext_vector_type(8)));   // 8 bf16 (4 VGPRs)
typedef float   f32x4  __attribute__((ext_vector_type(4)));

__device__ __forceinline__ unsigned short f2bf(float f) {
    unsigned int u = __float_as_uint(f);
    u += 0x7fffu + ((u >> 16) & 1u);   // round-to-nearest-even
    return (unsigned short)(u >> 16);
}
__device__ __forceinline__ void async16(const void* g, void* l) {
    __builtin_amdgcn_global_load_lds(
        (const __attribute__((address_space(1))) void*)g,
        (__attribute__((address_space(3))) void*)l, 16, 0, 0);
}

// ---- Prep: effective weights -> blocked+swizzled bf16 layout.
// Logical: row rW (z/h interleaved) x col k; cols [0:D)=W1, [D:2D)=W3-W1*mu.
// Physical: [nt 8][ks 16][row 256][32], k-quad kq stored at qp = kq ^ ((row>>1)&3).
__global__ void build_wb(const float* __restrict__ Wz, const float* __restrict__ Wh,
                         const float* __restrict__ xm, unsigned short* __restrict__ Wb) {
    int id  = blockIdx.x * 256 + threadIdx.x;      // uint4 id; total 2048*64
    int kq  = id & 3;
    int row = (id >> 2) & 255;
    int ks  = (id >> 10) & 15;
    int nt  = id >> 14;
    int rW  = nt * 256 + row;
    int m   = rW >> 1;
    const float* W = (rW & 1) ? (Wh + (size_t)m * 768) : (Wz + (size_t)m * 768);
    int k = ks * 32 + kq * 8;
    unsigned short o[8];
    #pragma unroll
    for (int j = 0; j < 8; j++) {
        float v;
        if (k < D_) v = W[k + j];
        else { int d = k - D_ + j; v = W[2 * D_ + d] - W[d] * xm[d]; }
        o[j] = f2bf(v);
    }
    uint4 pk;
    pk.x = (unsigned)o[0] | ((unsigned)o[1] << 16);
    pk.y = (unsigned)o[2] | ((unsigned)o[3] << 16);
    pk.z = (unsigned)o[4] | ((unsigned)o[5] << 16);
    pk.w = (unsigned)o[6] | ((unsigned)o[7] << 16);
    size_t dst = ((size_t)(nt * 16 + ks) * 256 + row) * 32
               + (size_t)((kq ^ ((row >> 1) & 3)) * 8);
    *(uint4*)(Wb + dst) = pk;
}

// ---- Prep: cvec[r] = bias[r] + (W1[r,:] + W2[r,:]) . mu  (interleaved rows) ----
__global__ void build_cvec(const float* __restrict__ Wz, const float* __restrict__ bz,
                           const float* __restrict__ Wh, const float* __restrict__ bh,
                           const float* __restrict__ xm, float* __restrict__ cvec) {
    int r = blockIdx.x;           // 0..2047
    int m = r >> 1;
    int d = threadIdx.x;          // 0..255
    const float* W = (r & 1) ? (Wh + (size_t)m * 768) : (Wz + (size_t)m * 768);
    float v = (W[d] + W[D_ + d]) * xm[d];
    for (int off = 32; off; off >>= 1) v += __shfl_down(v, off);
    __shared__ float red[4];
    if ((d & 63) == 0) red[d >> 6] = v;
    __syncthreads();
    if (d == 0) {
        float bias = (r & 1) ? bh[m] : bz[m];
        cvec[r] = bias + red[0] + red[1] + red[2] + red[3];
    }
}

// ---- Build A rows -> blocked+swizzled bf16 [p 1024][ks 16][row 128][32].
// Row of panel p: b=(p&127)*4+(row>>5), t=(p>>7)*32+(row&31). Cols: [m*x | m]. ----
__global__ void build_inp2(const float* __restrict__ X, const float* __restrict__ Mm,
                           unsigned short* __restrict__ inp2) {
    int id  = blockIdx.x * 256 + threadIdx.x;      // uint4 id; total 1024*16*128*4
    int kq  = id & 3;
    int row = (id >> 2) & 127;
    int ks  = (id >> 9) & 15;
    int p   = id >> 13;
    int b   = (p & 127) * 4 + (row >> 5);
    int t   = (p >> 7) * 32 + (row & 31);
    int k   = ks * 32 + kq * 8;
    const size_t rbase = ((size_t)b * T_ + t) * D_;
    unsigned short o[8];
    if (k < D_) {
        const float4* xp = (const float4*)(X  + rbase + k);
        const float4* mp = (const float4*)(Mm + rbase + k);
        float4 x0 = xp[0], x1 = xp[1], m0 = mp[0], m1 = mp[1];
        o[0]=f2bf(m0.x*x0.x); o[1]=f2bf(m0.y*x0.y); o[2]=f2bf(m0.z*x0.z); o[3]=f2bf(m0.w*x0.w);
        o[4]=f2bf(m1.x*x1.x); o[5]=f2bf(m1.y*x1.y); o[6]=f2bf(m1.z*x1.z); o[7]=f2bf(m1.w*x1.w);
    } else {
        const float4* mp = (const float4*)(Mm + rbase + (k - D_));
        float4 m0 = mp[0], m1 = mp[1];
        o[0]=f2bf(m0.x); o[1]=f2bf(m0.y); o[2]=f2bf(m0.z); o[3]=f2bf(m0.w);
        o[4]=f2bf(m1.x); o[5]=f2bf(m1.y); o[6]=f2bf(m1.z); o[7]=f2bf(m1.w);
    }
    uint4 pk;
    pk.x = (unsigned)o[0] | ((unsigned)o[1] << 16);
    pk.y = (unsigned)o[2] | ((unsigned)o[3] << 16);
    pk.z = (unsigned)o[4] | ((unsigned)o[5] << 16);
    pk.w = (unsigned)o[6] | ((unsigned)o[7] << 16);
    size_t dst = ((size_t)(p * 16 + ks) * 128 + row) * 32
               + (size_t)((kq ^ ((row >> 1) & 3)) * 8);
    *(uint4*)(inp2 + dst) = pk;
}

// ---- Fused GEMM + activation + chunk-local scan.
// Tile 128x256, BK=32, 8 waves (wave-tile 64x64), 48 KB LDS, VGPR<=128 ->
// 2 blocks/CU (inter-block overlap hides 2-phase barrier drains).
// Operands pre-blocked+swizzled: staging = linear global_load_lds (1 A + 2 B
// instr/thread/K-step); frag ds_read_b128 conflict-free (2 lanes/bank).
// Grid XCD-grouped: the 8 tn-sharers of an A-panel sit at blk stride 8 (same
// blk%8 -> same XCD, adjacent in dispatch) -> A HBM-streamed ~once.
// Epilogue: rcp-based activation + register pair-exchange + ordered butterfly
// scan -> store only (P,Q) per (chunk,batch,n).
__global__ __launch_bounds__(512, 4) void gemm_scan(
    const unsigned short* __restrict__ A,      // [1024][16][128][32] swizzled
    const unsigned short* __restrict__ Wb,     // [8][16][256][32] swizzled
    const float* __restrict__ cvec,            // [2048]
    float2* __restrict__ PQ)                   // [NCHUNK][B][1024]
{
    __shared__ __align__(16) unsigned short sm[24576];   // A 2x4096 | B 2x8192 (48 KB)
    const int tid  = threadIdx.x;
    const int lane = tid & 63;
    const int w    = tid >> 6;
    const int blk  = blockIdx.x;
    const int p    = (blk >> 6) * 8 + (blk & 7);   // panel 0..1023
    const int nt   = (blk >> 3) & 7;               // ntile 0..7
    const int c    = p >> 7;
    const int bg0  = (p & 127) * 4;

    const unsigned short* asrc = A  + (size_t)p  * 65536  + tid * 8;   // + ks*4096
    const unsigned short* bsrc = Wb + (size_t)nt * 131072 + tid * 8;   // + ks*8192

    const int wm = w >> 2, wn = w & 3;
    const int l15 = lane & 15, q = lane >> 4;

    // fragment LDS offsets (ushort units), buffer-relative, constant over K
    int aoff[4], boff[4];
    #pragma unroll
    for (int i = 0; i < 4; i++) {
        int row = wm * 64 + i * 16 + l15;
        aoff[i] = row * 32 + ((q ^ ((row >> 1) & 3)) * 8);
    }
    #pragma unroll
    for (int j = 0; j < 4; j++) {
        int rt = wn * 64 + j * 16 + l15;
        boff[j] = rt * 32 + ((q ^ ((rt >> 1) & 3)) * 8);
    }

    f32x4 acc[4][4] = {};

    // prologue: stage ks=0 into buf0
    async16(asrc,        sm + w * 512);
    async16(bsrc,        sm + 8192 + w * 512);
    async16(bsrc + 4096, sm + 8192 + 4096 + w * 512);
    __syncthreads();

    #pragma unroll
    for (int ks = 0; ks < 16; ++ks) {
        const int cur = ks & 1;
        if (ks < 15) {                         // prefetch next K-step (in flight over MFMA)
            const int nxt = cur ^ 1;
            async16(asrc + (ks + 1) * 4096,        sm + nxt * 4096 + w * 512);
            async16(bsrc + (ks + 1) * 8192,        sm + 8192 + nxt * 8192 + w * 512);
            async16(bsrc + (ks + 1) * 8192 + 4096, sm + 8192 + nxt * 8192 + 4096 + w * 512);
        }
        bf16x8 af[4], bv[4];
        #pragma unroll
        for (int i = 0; i < 4; i++)
            af[i] = *(const bf16x8*)&sm[cur * 4096 + aoff[i]];
        #pragma unroll
        for (int j = 0; j < 4; j++)
            bv[j] = *(const bf16x8*)&sm[8192 + cur * 8192 + boff[j]];
        #pragma unroll
        for (int i = 0; i < 4; i++)
            #pragma unroll
            for (int j = 0; j < 4; j++)
                acc[i][j] = __builtin_amdgcn_mfma_f32_16x16x32_bf16(af[i], bv[j], acc[i][j], 0, 0, 0);
        __syncthreads();             // drains prefetch (vmcnt) + frees read buffer
    }

    // ---- epilogue (registers only): activation + pair exchange + affine scan ----
    const float par = (float)(lane & 1);   // col parity: 0 => z (sigmoid), 1 => h~ (tanh)
    const float sg  = 1.f + par;           // sigmoid: 1/(1+e^-v); tanh: 2/(1+e^-2v)-1
    #pragma unroll
    for (int j = 0; j < 4; ++j) {
        const int ncol = nt * 256 + wn * 64 + j * 16 + l15;
        const float cadd = cvec[ncol];
        #pragma unroll
        for (int bl2 = 0; bl2 < 2; ++bl2) {
            // lane holds rows tc = i2*16 + q*4 + r of batch (bg0 + wm*2 + bl2)
            float PA = 1.f, QA = 0.f, PB = 1.f, QB = 0.f;
            #pragma unroll
            for (int r = 0; r < 4; ++r) {
                {   // i2 = 0: t = q*4 + r
                    float v  = acc[bl2 * 2][j][r] + cadd;
                    float a  = sg * __builtin_amdgcn_rcpf(1.f + __expf(-sg * v)) - par;
                    float ap = __shfl_xor(a, 1);
                    float z  = (lane & 1) ? ap : a;
                    float ht = (lane & 1) ? a : ap;
                    float om = 1.f - z;
                    QA = om * QA + z * ht;
                    PA = om * PA;
                }
                {   // i2 = 1: t = 16 + q*4 + r
                    float v  = acc[bl2 * 2 + 1][j][r] + cadd;
                    float a  = sg * __builtin_amdgcn_rcpf(1.f + __expf(-sg * v)) - par;
                    float ap = __shfl_xor(a, 1);
                    float z  = (lane & 1) ? ap : a;
                    float ht = (lane & 1) ? a : ap;
                    float om = 1.f - z;
                    QB = om * QB + z * ht;
                    PB = om * PB;
                }
            }
            // ordered butterfly over q (lane bits 4,5): lower q = earlier time
            #pragma unroll
            for (int s = 16; s <= 32; s <<= 1) {
                float PAp = __shfl_xor(PA, s), QAp = __shfl_xor(QA, s);
                float PBp = __shfl_xor(PB, s), QBp = __shfl_xor(QB, s);
                const bool late = (lane & s) != 0;
                float Pe = late ? PAp : PA,  Qe = late ? QAp : QA;
                float Pl = late ? PA  : PAp, Ql = late ? QA  : QAp;
                PA = Pl * Pe;  QA = Pl * Qe + Ql;
                Pe = late ? PBp : PB;  Qe = late ? QBp : QB;
                Pl = late ? PB  : PBp; Ql = late ? QB  : QBp;
                PB = Pl * Pe;  QB = Pl * Qe + Ql;
            }
            // total over 32 steps: apply A (t=0..15) then B (t=16..31)
            const float Ptot = PB * PA;
            const float Qtot = PB * QA + QB;
            if ((q == bl2 * 2) && ((lane & 1) == 0)) {
                const int npg = ncol >> 1;                 // original hidden idx
                const int bgl = bg0 + wm * 2 + bl2;
                PQ[((size_t)c * B_ + bgl) * H_ + npg] = make_float2(Ptot, Qtot);
            }
        }
    }
}

// ---- Combine the 8 chunk-affine maps: h = P_c*h + Q_c, c = 0..7 ----
__global__ void combine(const float2* __restrict__ PQ, float* __restrict__ hbuf) {
    int v = blockIdx.x * 256 + threadIdx.x;   // B*H threads
    int b = v >> 10;
    int n = v & 1023;
    float h = 0.f;
    #pragma unroll
    for (int c = 0; c < NCHUNK; c++) {
        float2 pq = PQ[((size_t)c * B_ + b) * H_ + n];
        h = pq.x * h + pq.y;
    }
    hbuf[(size_t)b * H_ + n] = h;
}

// ---- Output head: out[b] = sigmoid(h[b,:] . Wout + bout) ----
__global__ void head(const float* __restrict__ hbuf, const float* __restrict__ Wout,
                     const float* __restrict__ bout, float* __restrict__ out) {
    int b = blockIdx.x;
    float s = 0.f;
    for (int n = threadIdx.x; n < H_; n += 256)
        s += hbuf[(size_t)b * H_ + n] * Wout[n];
    for (int off = 32; off; off >>= 1) s += __shfl_down(s, off);
    __shared__ float red[4];
    if ((threadIdx.x & 63) == 0) red[threadIdx.x >> 6] = s;
    __syncthreads();
    if (threadIdx.x == 0) {
        float t = red[0] + red[1] + red[2] + red[3] + bout[0];
        out[b] = 1.f / (1.f + expf(-t));
    }
}

extern "C" void kernel_launch(void* const* d_in, const int* in_sizes, int n_in,
                              void* d_out, int out_size, void* d_ws, size_t ws_size,
                              hipStream_t stream) {
    const float* X    = (const float*)d_in[0];
    const float* Mm   = (const float*)d_in[1];
    const float* xm   = (const float*)d_in[2];
    // d_in[3]=gamma_x: algebraically irrelevant for binary masks (x_tilde == m*x+(1-m)*mu)
    const float* Wz   = (const float*)d_in[4];
    const float* bz   = (const float*)d_in[5];
    // d_in[6]=Wr, d_in[7]=br: dead code in reference (r_t unused) — skipped
    const float* Wh   = (const float*)d_in[8];
    const float* bh   = (const float*)d_in[9];
    const float* Wout = (const float*)d_in[10];
    const float* bout = (const float*)d_in[11];
    float* out = (float*)d_out;

    char* ws = (char*)d_ws;
    unsigned short* Wb    = (unsigned short*)(ws + OFF_WB);
    float*          cvec  = (float*)(ws + OFF_CVEC);
    float*          hbuf  = (float*)(ws + OFF_H);
    float2*         PQ    = (float2*)(ws + OFF_PQ);
    unsigned short* inp2  = (unsigned short*)(ws + OFF_INP2);

    build_wb  <<<dim3(512),  dim3(256), 0, stream>>>(Wz, Wh, xm, Wb);
    build_cvec<<<dim3(N2),   dim3(256), 0, stream>>>(Wz, bz, Wh, bh, xm, cvec);
    build_inp2<<<dim3(32768), dim3(256), 0, stream>>>(X, Mm, inp2);

    // grid = 1024 panels x 8 ntiles, XCD-grouped (panel sharers at stride 8)
    gemm_scan<<<dim3(8192), dim3(512), 0, stream>>>(inp2, Wb, cvec, PQ);

    combine<<<dim3(B_ * H_ / 256), dim3(256), 0, stream>>>(PQ, hbuf);
    head   <<<dim3(B_),            dim3(256), 0, stream>>>(hbuf, Wout, bout, out);
}

// Round 5
// 696.083 us; speedup vs baseline: 2.2570x; 1.0372x over previous
//
#include <hip/hip_runtime.h>
#include <cstdint>
#include <cstddef>

// Problem constants
#define B_  512
#define T_  256
#define D_  256
#define H_  1024
#define K2  512      // effective K = 2*D: [ m*x | m ]; mu-path folded into cvec/Wb
#define N2  2048     // interleaved outputs: col 2m = z preact, col 2m+1 = h_til preact
#define TC  32       // timesteps per chunk
#define NCHUNK 8     // TC*NCHUNK == T_

// Workspace layout (bytes). ~166 MB.
#define OFF_WB    ((size_t)0)                      // bf16 [8][16][256][32]       2 MB
#define OFF_CVEC  ((size_t)2097152)                // f32  [2048]                 8 KB
#define OFF_H     ((size_t)2105344)                // f32  [B][H]                 2 MB
#define OFF_PQ    ((size_t)4202496)                // f32x2 [NCHUNK][B][H]       32 MB
#define OFF_INP2  ((size_t)37756928)               // bf16 [1024][16][128][32]  128 MB

typedef short   bf16x8 __attribute__((ext_vector_type(8)));   // 8 bf16 (4 VGPRs)
typedef float   f32x4  __attribute__((ext_vector_type(4)));

__device__ __forceinline__ unsigned short f2bf(float f) {
    unsigned int u = __float_as_uint(f);
    u += 0x7fffu + ((u >> 16) & 1u);   // round-to-nearest-even
    return (unsigned short)(u >> 16);
}
__device__ __forceinline__ void async16(const void* g, void* l) {
    __builtin_amdgcn_global_load_lds(
        (const __attribute__((address_space(1))) void*)g,
        (__attribute__((address_space(3))) void*)l, 16, 0, 0);
}

// ---- Prep: effective weights -> blocked+swizzled bf16 layout.
// Logical: row rW (z/h interleaved) x col k; cols [0:D)=W1, [D:2D)=W3-W1*mu.
// Physical: [nt 8][ks 16][row 256][32], k-quad kq stored at qp = kq ^ ((row>>1)&3).
__global__ void build_wb(const float* __restrict__ Wz, const float* __restrict__ Wh,
                         const float* __restrict__ xm, unsigned short* __restrict__ Wb) {
    int id  = blockIdx.x * 256 + threadIdx.x;      // uint4 id; total 2048*64
    int kq  = id & 3;
    int row = (id >> 2) & 255;
    int ks  = (id >> 10) & 15;
    int nt  = id >> 14;
    int rW  = nt * 256 + row;
    int m   = rW >> 1;
    const float* W = (rW & 1) ? (Wh + (size_t)m * 768) : (Wz + (size_t)m * 768);
    int k = ks * 32 + kq * 8;
    unsigned short o[8];
    #pragma unroll
    for (int j = 0; j < 8; j++) {
        float v;
        if (k < D_) v = W[k + j];
        else { int d = k - D_ + j; v = W[2 * D_ + d] - W[d] * xm[d]; }
        o[j] = f2bf(v);
    }
    uint4 pk;
    pk.x = (unsigned)o[0] | ((unsigned)o[1] << 16);
    pk.y = (unsigned)o[2] | ((unsigned)o[3] << 16);
    pk.z = (unsigned)o[4] | ((unsigned)o[5] << 16);
    pk.w = (unsigned)o[6] | ((unsigned)o[7] << 16);
    size_t dst = ((size_t)(nt * 16 + ks) * 256 + row) * 32
               + (size_t)((kq ^ ((row >> 1) & 3)) * 8);
    *(uint4*)(Wb + dst) = pk;
}

// ---- Prep: cvec[r] = bias[r] + (W1[r,:] + W2[r,:]) . mu  (interleaved rows) ----
__global__ void build_cvec(const float* __restrict__ Wz, const float* __restrict__ bz,
                           const float* __restrict__ Wh, const float* __restrict__ bh,
                           const float* __restrict__ xm, float* __restrict__ cvec) {
    int r = blockIdx.x;           // 0..2047
    int m = r >> 1;
    int d = threadIdx.x;          // 0..255
    const float* W = (r & 1) ? (Wh + (size_t)m * 768) : (Wz + (size_t)m * 768);
    float v = (W[d] + W[D_ + d]) * xm[d];
    for (int off = 32; off; off >>= 1) v += __shfl_down(v, off);
    __shared__ float red[4];
    if ((d & 63) == 0) red[d >> 6] = v;
    __syncthreads();
    if (d == 0) {
        float bias = (r & 1) ? bh[m] : bz[m];
        cvec[r] = bias + red[0] + red[1] + red[2] + red[3];
    }
}

// ---- Build A rows -> blocked+swizzled bf16 [p 1024][ks 16][row 128][32].
// Row of panel p: b=(p&127)*4+(row>>5), t=(p>>7)*32+(row&31). Cols: [m*x | m]. ----
__global__ void build_inp2(const float* __restrict__ X, const float* __restrict__ Mm,
                           unsigned short* __restrict__ inp2) {
    int id  = blockIdx.x * 256 + threadIdx.x;      // uint4 id; total 1024*16*128*4
    int kq  = id & 3;
    int row = (id >> 2) & 127;
    int ks  = (id >> 9) & 15;
    int p   = id >> 13;
    int b   = (p & 127) * 4 + (row >> 5);
    int t   = (p >> 7) * 32 + (row & 31);
    int k   = ks * 32 + kq * 8;
    const size_t rbase = ((size_t)b * T_ + t) * D_;
    unsigned short o[8];
    if (k < D_) {
        const float4* xp = (const float4*)(X  + rbase + k);
        const float4* mp = (const float4*)(Mm + rbase + k);
        float4 x0 = xp[0], x1 = xp[1], m0 = mp[0], m1 = mp[1];
        o[0]=f2bf(m0.x*x0.x); o[1]=f2bf(m0.y*x0.y); o[2]=f2bf(m0.z*x0.z); o[3]=f2bf(m0.w*x0.w);
        o[4]=f2bf(m1.x*x1.x); o[5]=f2bf(m1.y*x1.y); o[6]=f2bf(m1.z*x1.z); o[7]=f2bf(m1.w*x1.w);
    } else {
        const float4* mp = (const float4*)(Mm + rbase + (k - D_));
        float4 m0 = mp[0], m1 = mp[1];
        o[0]=f2bf(m0.x); o[1]=f2bf(m0.y); o[2]=f2bf(m0.z); o[3]=f2bf(m0.w);
        o[4]=f2bf(m1.x); o[5]=f2bf(m1.y); o[6]=f2bf(m1.z); o[7]=f2bf(m1.w);
    }
    uint4 pk;
    pk.x = (unsigned)o[0] | ((unsigned)o[1] << 16);
    pk.y = (unsigned)o[2] | ((unsigned)o[3] << 16);
    pk.z = (unsigned)o[4] | ((unsigned)o[5] << 16);
    pk.w = (unsigned)o[6] | ((unsigned)o[7] << 16);
    size_t dst = ((size_t)(p * 16 + ks) * 128 + row) * 32
               + (size_t)((kq ^ ((row >> 1) & 3)) * 8);
    *(uint4*)(inp2 + dst) = pk;
}

// ---- Fused GEMM + activation + chunk-local scan.
// Tile 128x256, BK=32, 8 waves (wave-tile 64x64). Pipeline: 3-deep LDS ring
// (72 KB -> 2 blocks/CU) with T4 counted-vmcnt discipline:
//   STAGE(ks+2) ; s_waitcnt vmcnt(6) ; s_barrier ; ds_read+MFMA ; s_barrier
// Raw s_barrier (inline asm, memory clobber) — NO vmcnt(0) drain ever in the
// loop; 6 loads stay in flight across barriers. vmcnt(6) + barrier => every
// wave's buffer-ks loads landed before any wave reads it. Buffer reuse is
// safe: stage of phys buffer P for iter ks is issued at iter ks-2, after the
// post-MFMA barrier of iter ks-3 (the last read of P).
// Operands pre-blocked+swizzled: staging = 3 linear global_load_lds/thread/
// iter; frag ds_read_b128 conflict-free. Grid XCD-grouped (panel sharers at
// blk stride 8) -> A HBM-streamed ~once. Epilogue unchanged (round-4-verified).
__global__ __launch_bounds__(512, 4) void gemm_scan(
    const unsigned short* __restrict__ A,      // [1024][16][128][32] swizzled
    const unsigned short* __restrict__ Wb,     // [8][16][256][32] swizzled
    const float* __restrict__ cvec,            // [2048]
    float2* __restrict__ PQ)                   // [NCHUNK][B][1024]
{
    __shared__ __align__(16) unsigned short sm[36864];   // A 3x4096 | B 3x8192 (72 KB)
    const int tid  = threadIdx.x;
    const int lane = tid & 63;
    const int w    = tid >> 6;
    const int blk  = blockIdx.x;
    const int p    = (blk >> 6) * 8 + (blk & 7);   // panel 0..1023
    const int nt   = (blk >> 3) & 7;               // ntile 0..7
    const int c    = p >> 7;
    const int bg0  = (p & 127) * 4;

    const unsigned short* asrc = A  + (size_t)p  * 65536  + tid * 8;   // + ks*4096
    const unsigned short* bsrc = Wb + (size_t)nt * 131072 + tid * 8;   // + ks*8192

    const int wm = w >> 2, wn = w & 3;
    const int l15 = lane & 15, q = lane >> 4;

    // fragment LDS offsets (ushort units), ring-buffer-relative, constant over K
    int aoff[4], boff[4];
    #pragma unroll
    for (int i = 0; i < 4; i++) {
        int row = wm * 64 + i * 16 + l15;
        aoff[i] = row * 32 + ((q ^ ((row >> 1) & 3)) * 8);
    }
    #pragma unroll
    for (int j = 0; j < 4; j++) {
        int rt = wn * 64 + j * 16 + l15;
        boff[j] = rt * 32 + ((q ^ ((rt >> 1) & 3)) * 8);
    }

// ring buffers: A at sm + r*4096, B at sm + 12288 + r*8192 (ushort units)
#define STAGE(rng, ks_)                                                          \
    { async16(asrc + (ks_) * 4096,        sm + (rng) * 4096 + w * 512);          \
      async16(bsrc + (size_t)(ks_) * 8192,        sm + 12288 + (rng) * 8192 + w * 512); \
      async16(bsrc + (size_t)(ks_) * 8192 + 4096, sm + 12288 + (rng) * 8192 + 4096 + w * 512); }

    f32x4 acc[4][4] = {};

    STAGE(0, 0);
    STAGE(1, 1);

    #pragma unroll
    for (int ks = 0; ks < 16; ++ks) {
        const int cur = ks % 3;
        if (ks + 2 < 16) STAGE((ks + 2) % 3, ks + 2);
        // wait for buffer `ks` (3 loads/iter; 2 newer stages may stay in flight)
        if (ks < 14)       asm volatile("s_waitcnt vmcnt(6)" ::: "memory");
        else if (ks == 14) asm volatile("s_waitcnt vmcnt(3)" ::: "memory");
        else               asm volatile("s_waitcnt vmcnt(0)" ::: "memory");
        asm volatile("s_barrier" ::: "memory");   // raw: no drain of newer loads

        bf16x8 af[4], bv[4];
        #pragma unroll
        for (int i = 0; i < 4; i++)
            af[i] = *(const bf16x8*)&sm[cur * 4096 + aoff[i]];
        #pragma unroll
        for (int j = 0; j < 4; j++)
            bv[j] = *(const bf16x8*)&sm[12288 + cur * 8192 + boff[j]];
        __builtin_amdgcn_s_setprio(1);
        #pragma unroll
        for (int i = 0; i < 4; i++)
            #pragma unroll
            for (int j = 0; j < 4; j++)
                acc[i][j] = __builtin_amdgcn_mfma_f32_16x16x32_bf16(af[i], bv[j], acc[i][j], 0, 0, 0);
        __builtin_amdgcn_s_setprio(0);
        asm volatile("s_barrier" ::: "memory");   // all reads of buf `cur` done
    }
#undef STAGE

    // ---- epilogue (registers only): activation + pair exchange + affine scan ----
    const float par = (float)(lane & 1);   // col parity: 0 => z (sigmoid), 1 => h~ (tanh)
    const float sg  = 1.f + par;           // sigmoid: 1/(1+e^-v); tanh: 2/(1+e^-2v)-1
    #pragma unroll
    for (int j = 0; j < 4; ++j) {
        const int ncol = nt * 256 + wn * 64 + j * 16 + l15;
        const float cadd = cvec[ncol];
        #pragma unroll
        for (int bl2 = 0; bl2 < 2; ++bl2) {
            // lane holds rows tc = i2*16 + q*4 + r of batch (bg0 + wm*2 + bl2)
            float PA = 1.f, QA = 0.f, PB = 1.f, QB = 0.f;
            #pragma unroll
            for (int r = 0; r < 4; ++r) {
                {   // i2 = 0: t = q*4 + r
                    float v  = acc[bl2 * 2][j][r] + cadd;
                    float a  = sg * __builtin_amdgcn_rcpf(1.f + __expf(-sg * v)) - par;
                    float ap = __shfl_xor(a, 1);
                    float z  = (lane & 1) ? ap : a;
                    float ht = (lane & 1) ? a : ap;
                    float om = 1.f - z;
                    QA = om * QA + z * ht;
                    PA = om * PA;
                }
                {   // i2 = 1: t = 16 + q*4 + r
                    float v  = acc[bl2 * 2 + 1][j][r] + cadd;
                    float a  = sg * __builtin_amdgcn_rcpf(1.f + __expf(-sg * v)) - par;
                    float ap = __shfl_xor(a, 1);
                    float z  = (lane & 1) ? ap : a;
                    float ht = (lane & 1) ? a : ap;
                    float om = 1.f - z;
                    QB = om * QB + z * ht;
                    PB = om * PB;
                }
            }
            // ordered butterfly over q (lane bits 4,5): lower q = earlier time
            #pragma unroll
            for (int s = 16; s <= 32; s <<= 1) {
                float PAp = __shfl_xor(PA, s), QAp = __shfl_xor(QA, s);
                float PBp = __shfl_xor(PB, s), QBp = __shfl_xor(QB, s);
                const bool late = (lane & s) != 0;
                float Pe = late ? PAp : PA,  Qe = late ? QAp : QA;
                float Pl = late ? PA  : PAp, Ql = late ? QA  : QAp;
                PA = Pl * Pe;  QA = Pl * Qe + Ql;
                Pe = late ? PBp : PB;  Qe = late ? QBp : QB;
                Pl = late ? PB  : PBp; Ql = late ? QB  : QBp;
                PB = Pl * Pe;  QB = Pl * Qe + Ql;
            }
            // total over 32 steps: apply A (t=0..15) then B (t=16..31)
            const float Ptot = PB * PA;
            const float Qtot = PB * QA + QB;
            if ((q == bl2 * 2) && ((lane & 1) == 0)) {
                const int npg = ncol >> 1;                 // original hidden idx
                const int bgl = bg0 + wm * 2 + bl2;
                PQ[((size_t)c * B_ + bgl) * H_ + npg] = make_float2(Ptot, Qtot);
            }
        }
    }
}

// ---- Combine the 8 chunk-affine maps: h = P_c*h + Q_c, c = 0..7 ----
__global__ void combine(const float2* __restrict__ PQ, float* __restrict__ hbuf) {
    int v = blockIdx.x * 256 + threadIdx.x;   // B*H threads
    int b = v >> 10;
    int n = v & 1023;
    float h = 0.f;
    #pragma unroll
    for (int c = 0; c < NCHUNK; c++) {
        float2 pq = PQ[((size_t)c * B_ + b) * H_ + n];
        h = pq.x * h + pq.y;
    }
    hbuf[(size_t)b * H_ + n] = h;
}

// ---- Output head: out[b] = sigmoid(h[b,:] . Wout + bout) ----
__global__ void head(const float* __restrict__ hbuf, const float* __restrict__ Wout,
                     const float* __restrict__ bout, float* __restrict__ out) {
    int b = blockIdx.x;
    float s = 0.f;
    for (int n = threadIdx.x; n < H_; n += 256)
        s += hbuf[(size_t)b * H_ + n] * Wout[n];
    for (int off = 32; off; off >>= 1) s += __shfl_down(s, off);
    __shared__ float red[4];
    if ((threadIdx.x & 63) == 0) red[threadIdx.x >> 6] = s;
    __syncthreads();
    if (threadIdx.x == 0) {
        float t = red[0] + red[1] + red[2] + red[3] + bout[0];
        out[b] = 1.f / (1.f + expf(-t));
    }
}

extern "C" void kernel_launch(void* const* d_in, const int* in_sizes, int n_in,
                              void* d_out, int out_size, void* d_ws, size_t ws_size,
                              hipStream_t stream) {
    const float* X    = (const float*)d_in[0];
    const float* Mm   = (const float*)d_in[1];
    const float* xm   = (const float*)d_in[2];
    // d_in[3]=gamma_x: algebraically irrelevant for binary masks (x_tilde == m*x+(1-m)*mu)
    const float* Wz   = (const float*)d_in[4];
    const float* bz   = (const float*)d_in[5];
    // d_in[6]=Wr, d_in[7]=br: dead code in reference (r_t unused) — skipped
    const float* Wh   = (const float*)d_in[8];
    const float* bh   = (const float*)d_in[9];
    const float* Wout = (const float*)d_in[10];
    const float* bout = (const float*)d_in[11];
    float* out = (float*)d_out;

    char* ws = (char*)d_ws;
    unsigned short* Wb    = (unsigned short*)(ws + OFF_WB);
    float*          cvec  = (float*)(ws + OFF_CVEC);
    float*          hbuf  = (float*)(ws + OFF_H);
    float2*         PQ    = (float2*)(ws + OFF_PQ);
    unsigned short* inp2  = (unsigned short*)(ws + OFF_INP2);

    build_wb  <<<dim3(512),  dim3(256), 0, stream>>>(Wz, Wh, xm, Wb);
    build_cvec<<<dim3(N2),   dim3(256), 0, stream>>>(Wz, bz, Wh, bh, xm, cvec);
    build_inp2<<<dim3(32768), dim3(256), 0, stream>>>(X, Mm, inp2);

    // grid = 1024 panels x 8 ntiles, XCD-grouped (panel sharers at stride 8)
    gemm_scan<<<dim3(8192), dim3(512), 0, stream>>>(inp2, Wb, cvec, PQ);

    combine<<<dim3(B_ * H_ / 256), dim3(256), 0, stream>>>(PQ, hbuf);
    head   <<<dim3(B_),            dim3(256), 0, stream>>>(hbuf, Wout, bout, out);
}